// Round 7
// baseline (346.322 us; speedup 1.0000x reference)
//
#include <hip/hip_runtime.h>
#include <math.h>

#define DM 1024
#define NH 16
#define DK 64
#define BB 4
#define TT 2048
#define MTOT (BB*TT)   // 8192

typedef __bf16 bf16x8 __attribute__((ext_vector_type(8)));
typedef short  s16x4  __attribute__((ext_vector_type(4)));
typedef float  f32x4  __attribute__((ext_vector_type(4)));

__device__ __forceinline__ short f2bf_s(float f) {
    __bf16 h = (__bf16)f;
    return __builtin_bit_cast(short, h);
}

// async global->LDS, 16B per lane; LDS dst wave-uniform base, lane i -> base+16i
__device__ __forceinline__ void async_copy16(unsigned short* lds, const unsigned short* g) {
    __builtin_amdgcn_global_load_lds(
        (const __attribute__((address_space(1))) unsigned int*)g,
        (__attribute__((address_space(3))) unsigned int*)lds, 16, 0, 0);
}

// ---------------------------------------------------------------------------
// merged fp32 -> bf16 converts
// ---------------------------------------------------------------------------
__global__ __launch_bounds__(256)
void cvt_all_kernel(const float* __restrict__ x,
                    const float* __restrict__ wq, const float* __restrict__ wk,
                    const float* __restrict__ wv, const float* __restrict__ wo,
                    unsigned short* __restrict__ xb,
                    unsigned short* __restrict__ wqb, unsigned short* __restrict__ wkb,
                    unsigned short* __restrict__ wvb, unsigned short* __restrict__ wob)
{
    const int XB = (MTOT * DM) / 1024;   // 8192
    int bz = blockIdx.x;
    const float* src; unsigned short* dst; int blk;
    if (bz < XB) { src = x; dst = xb; blk = bz; }
    else {
        int t = bz - XB, which = t >> 10;
        blk = t & 1023;
        if (which == 0)      { src = wq; dst = wqb; }
        else if (which == 1) { src = wk; dst = wkb; }
        else if (which == 2) { src = wv; dst = wvb; }
        else                 { src = wo; dst = wob; }
    }
    int i = blk * 256 + threadIdx.x;
    float4 v = ((const float4*)src)[i];
    ushort4 o;
    o.x = (unsigned short)f2bf_s(v.x); o.y = (unsigned short)f2bf_s(v.y);
    o.z = (unsigned short)f2bf_s(v.z); o.w = (unsigned short)f2bf_s(v.w);
    ((ushort4*)dst)[i] = o;
}

// ---------------------------------------------------------------------------
// bf16 MFMA GEMM, BK=64, XOR-swizzled LDS, global_load_lds staging.
// MODE 0: fp32 row-major out. MODE 1: bf16 (B,H,T,DK); z=0 Q(+RoPE+prescale),
// z=1 K(+RoPE), z=2 V plain.
// ---------------------------------------------------------------------------
template<int MODE>
__global__ __launch_bounds__(256, 3)
void gemm_bf16_kernel(const unsigned short* __restrict__ X,
                      const unsigned short* __restrict__ W0, const float* __restrict__ b0,
                      const unsigned short* __restrict__ W1, const float* __restrict__ b1,
                      const unsigned short* __restrict__ W2, const float* __restrict__ b2,
                      void* __restrict__ Y0, void* __restrict__ Y1, void* __restrict__ Y2)
{
    const unsigned short* W; const float* bias; void* Yv;
    const int z = blockIdx.z;
    if (z == 0)      { W = W0; bias = b0; Yv = Y0; }
    else if (z == 1) { W = W1; bias = b1; Yv = Y1; }
    else             { W = W2; bias = b2; Yv = Y2; }

    __shared__ __align__(16) unsigned short As[128 * 64];  // 16 KB
    __shared__ __align__(16) unsigned short Bs[128 * 64];  // 16 KB

    const int tid  = threadIdx.x;
    const int w    = tid >> 6, lane = tid & 63;
    const int quad = lane >> 4, lq = lane & 15;
    const int bm = blockIdx.x * 128, bn = blockIdx.y * 128;
    const int wm = (w >> 1) * 64,   wn = (w & 1) * 64;

    const int srow = lane >> 3;                 // 0..7 within the 8-row group
    const int sg   = (lane & 7) ^ srow;         // swizzled source granule
    const int soff = sg * 8;                    // shorts

    f32x4 acc[4][4];
    #pragma unroll
    for (int i = 0; i < 4; ++i)
        #pragma unroll
        for (int j = 0; j < 4; ++j)
            acc[i][j] = {0.f, 0.f, 0.f, 0.f};

    for (int k0 = 0; k0 < DM; k0 += 64) {
        #pragma unroll
        for (int c = 0; c < 4; ++c) {
            int r0 = w * 32 + c * 8;
            async_copy16(&As[r0 * 64], &X[(size_t)(bm + r0 + srow) * DM + k0 + soff]);
            async_copy16(&Bs[r0 * 64], &W[(size_t)(bn + r0 + srow) * DM + k0 + soff]);
        }
        __syncthreads();

        #pragma unroll
        for (int ks = 0; ks < 2; ++ks) {
            const int gsw = ((ks << 2) + quad) ^ (lq & 7);  // physical granule
            bf16x8 af[4], bfr[4];
            #pragma unroll
            for (int i = 0; i < 4; ++i)
                af[i] = *(const bf16x8*)&As[(wm + i*16 + lq) * 64 + gsw * 8];
            #pragma unroll
            for (int j = 0; j < 4; ++j)
                bfr[j] = *(const bf16x8*)&Bs[(wn + j*16 + lq) * 64 + gsw * 8];
            #pragma unroll
            for (int i = 0; i < 4; ++i)
                #pragma unroll
                for (int j = 0; j < 4; ++j)
                    acc[i][j] = __builtin_amdgcn_mfma_f32_16x16x32_bf16(af[i], bfr[j], acc[i][j], 0, 0, 0);
        }
        __syncthreads();
    }

    if (MODE == 0) {
        #pragma unroll
        for (int j = 0; j < 4; ++j) {
            int n = bn + wn + j*16 + lq;
            float bv = bias[n];
            #pragma unroll
            for (int i = 0; i < 4; ++i)
                #pragma unroll
                for (int r = 0; r < 4; ++r) {
                    int m = bm + wm + i*16 + quad*4 + r;
                    ((float*)Yv)[(size_t)m * DM + n] = acc[i][j][r] + bv;
                }
        }
    } else if (z == 2) {
        #pragma unroll
        for (int j = 0; j < 4; ++j) {
            int n = bn + wn + j*16 + lq;
            float bv = bias[n];
            int h = n >> 6, dk = n & 63;
            #pragma unroll
            for (int i = 0; i < 4; ++i)
                #pragma unroll
                for (int r = 0; r < 4; ++r) {
                    int m = bm + wm + i*16 + quad*4 + r;
                    int b = m >> 11, t = m & 2047;
                    ((__bf16*)Yv)[(((size_t)(b * NH + h) * TT + t) << 6) + dk] =
                        (__bf16)(acc[i][j][r] + bv);
                }
        }
    } else {
        // Q (z=0) / K (z=1): fused RoPE; Q also pre-scaled by 0.125*log2e
        const float QSC = (z == 0) ? 0.125f * 1.44269504f : 1.0f;
        const int h = (bn + wn) >> 6;
        #pragma unroll
        for (int jp = 0; jp < 2; ++jp) {
            int dk1 = jp * 16 + lq;                           // 0..31
            float freq = exp2f(-(float)dk1 * 0.4152410118f);  // 10000^(-dk1/32)
            float bv1 = bias[bn + wn + dk1];
            float bv2 = bias[bn + wn + dk1 + 32];
            #pragma unroll
            for (int i = 0; i < 4; ++i) {
                #pragma unroll
                for (int r = 0; r < 4; ++r) {
                    int m = bm + wm + i*16 + quad*4 + r;
                    int b = m >> 11, t = m & 2047;
                    float ang = (float)t * freq;
                    float sn = __sinf(ang), cs = __cosf(ang);
                    float v1 = acc[i][jp][r]     + bv1;
                    float v2 = acc[i][jp + 2][r] + bv2;
                    float o1 = (v1 * cs - v2 * sn) * QSC;
                    float o2 = (v1 * sn + v2 * cs) * QSC;
                    size_t base = ((size_t)(b * NH + h) * TT + t) << 6;
                    ((__bf16*)Yv)[base + dk1]      = (__bf16)o1;
                    ((__bf16*)Yv)[base + dk1 + 32] = (__bf16)o2;
                }
            }
        }
    }
}

// ---------------------------------------------------------------------------
// V (B,H,T,DK) -> V^T (B,H,DK,T), coalesced both sides via LDS tile.
// ---------------------------------------------------------------------------
__global__ __launch_bounds__(256)
void vtrans_kernel(const unsigned short* __restrict__ V, unsigned short* __restrict__ Vt)
{
    __shared__ unsigned short tile[64][72];
    const int tid = threadIdx.x;
    const int t0 = blockIdx.x * 64;
    const int bh = blockIdx.y;
    const size_t ib = (size_t)bh * TT * DK;
    const size_t ob = (size_t)bh * DK * TT;
    #pragma unroll
    for (int p = 0; p < 2; ++p) {
        int s = p * 256 + tid;
        int r = s >> 3, c0 = (s & 7) * 8;
        *(uint4*)&tile[r][c0] = *(const uint4*)&V[ib + (size_t)(t0 + r) * DK + c0];
    }
    __syncthreads();
    #pragma unroll
    for (int p = 0; p < 2; ++p) {
        int s = p * 256 + tid;
        int dk = s >> 3, c0 = (s & 7) * 8;
        unsigned short tmp[8];
        #pragma unroll
        for (int e = 0; e < 8; ++e) tmp[e] = tile[c0 + e][dk];
        *(uint4*)&Vt[ob + (size_t)dk * TT + t0 + c0] = *(const uint4*)tmp;
    }
}

// ---------------------------------------------------------------------------
// MFMA flash attention (causal), S^T form, NO LDS: K and V^T fragments are
// loaded straight from global (L1/L2-cached; per-head K/V lives in one XCD's
// L2 thanks to the grid swizzle). 4 q-tiles per block {x,15-x,16+x,31-x} ->
// uniform 66 process-calls and 4-way fragment reuse per load. No barriers.
// Static-max softmax (scores bounded; shift-invariant). Grid (64, 8).
// ---------------------------------------------------------------------------
__global__ __launch_bounds__(256, 2)
void attn_kernel(const unsigned short* __restrict__ Q, const unsigned short* __restrict__ K,
                 const unsigned short* __restrict__ Vt_g, unsigned short* __restrict__ ctx)
{
    const int tid  = threadIdx.x;
    const int w    = tid >> 6, lane = tid & 63;
    const int quad = lane >> 4, lq = lane & 15;
    const int bh = blockIdx.x;
    const int x  = blockIdx.y;                  // 0..7
    const int qt[4] = { x, 15 - x, 16 + x, 31 - x };
    const size_t kbase = (size_t)bh * TT * DK;
    const size_t vbase = (size_t)bh * DK * TT;

    int   qrow[4];
    bf16x8 qf[4][2];
    #pragma unroll
    for (int i = 0; i < 4; ++i) {
        qrow[i] = qt[i]*64 + w*16 + lq;
        qf[i][0] = *(const bf16x8*)&Q[kbase + (size_t)qrow[i] * DK + quad*8];
        qf[i][1] = *(const bf16x8*)&Q[kbase + (size_t)qrow[i] * DK + 32 + quad*8];
    }

    f32x4 accO[4][4];
    float l_i[4] = {0.f, 0.f, 0.f, 0.f};
    #pragma unroll
    for (int i = 0; i < 4; ++i)
        #pragma unroll
        for (int dt = 0; dt < 4; ++dt) accO[i][dt] = {0.f,0.f,0.f,0.f};

    const int kbmax = qt[3];
    for (int kb = 0; kb <= kbmax; ++kb) {
        // ---- K fragments straight from global (16B/lane, L1-resident) ----
        bf16x8 kf[2][4];
        #pragma unroll
        for (int ks = 0; ks < 2; ++ks)
            #pragma unroll
            for (int nt = 0; nt < 4; ++nt)
                kf[ks][nt] = *(const bf16x8*)&K[kbase +
                    (size_t)(kb*64 + nt*16 + lq) * DK + ks*32 + quad*8];

        // ---- S^T + softmax for each active q-tile; P stays in registers ----
        s16x4 p[4][4];
        int nact = (kb <= qt[0]) ? 4 : (kb <= qt[1]) ? 3 : (kb <= qt[2]) ? 2 : 1;
        // active tiles are the LAST nact ones (qt ascending)
        #pragma unroll
        for (int i = 0; i < 4; ++i) {
            if (i < 4 - nact) continue;
            f32x4 st[4];
            #pragma unroll
            for (int nt = 0; nt < 4; ++nt) st[nt] = {0.f,0.f,0.f,0.f};
            #pragma unroll
            for (int ks = 0; ks < 2; ++ks)
                #pragma unroll
                for (int nt = 0; nt < 4; ++nt)
                    st[nt] = __builtin_amdgcn_mfma_f32_16x16x32_bf16(kf[ks][nt], qf[i][ks], st[nt], 0, 0, 0);
            if (kb == qt[i]) {
                #pragma unroll
                for (int nt = 0; nt < 4; ++nt)
                    #pragma unroll
                    for (int r = 0; r < 4; ++r) {
                        int kc = kb*64 + nt*16 + quad*4 + r;
                        if (kc > qrow[i]) st[nt][r] = -1e30f;
                    }
            }
            #pragma unroll
            for (int nt = 0; nt < 4; ++nt)
                #pragma unroll
                for (int r = 0; r < 4; ++r) {
                    float e = exp2f(st[nt][r]);
                    l_i[i] += e;
                    p[i][nt][r] = f2bf_s(e);
                }
        }

        // ---- PV: one vb load set shared by all active tiles ----
        #pragma unroll
        for (int kt = 0; kt < 4; ++kt) {
            s16x4 vb[4];
            #pragma unroll
            for (int dt = 0; dt < 4; ++dt)
                vb[dt] = *(const s16x4*)&Vt_g[vbase +
                    (size_t)(dt*16 + lq) * TT + kb*64 + kt*16 + quad*4];
            #pragma unroll
            for (int i = 0; i < 4; ++i) {
                if (i < 4 - nact) continue;
                #pragma unroll
                for (int dt = 0; dt < 4; ++dt)
                    accO[i][dt] = __builtin_amdgcn_mfma_f32_16x16x16bf16_1k(p[i][kt], vb[dt], accO[i][dt], 0, 0, 0);
            }
        }
    }

    // ---- epilogue ----
    const int b = bh >> 4, h = bh & 15;
    #pragma unroll
    for (int i = 0; i < 4; ++i) {
        float l = l_i[i];
        l += __shfl_xor(l, 16, 64);
        l += __shfl_xor(l, 32, 64);
        float linv = 1.0f / l;
        f32x4 il4;
        #pragma unroll
        for (int r = 0; r < 4; ++r) il4[r] = __shfl(linv, quad*4 + r, 64);
        #pragma unroll
        for (int r = 0; r < 4; ++r) {
            int t = qt[i]*64 + w*16 + quad*4 + r;
            size_t ob = ((size_t)b * TT + t) * DM + h * DK;
            #pragma unroll
            for (int dt = 0; dt < 4; ++dt)
                ((__bf16*)ctx)[ob + dt*16 + lq] = (__bf16)(accO[i][dt][r] * il4[r]);
        }
    }
}

// ---------------------------------------------------------------------------
extern "C" void kernel_launch(void* const* d_in, const int* in_sizes, int n_in,
                              void* d_out, int out_size, void* d_ws, size_t ws_size,
                              hipStream_t stream)
{
    const float* x   = (const float*)d_in[0];
    const float* WQw = (const float*)d_in[1];
    const float* WQb = (const float*)d_in[2];
    const float* WKw = (const float*)d_in[3];
    const float* WKb = (const float*)d_in[4];
    const float* WVw = (const float*)d_in[5];
    const float* WVb = (const float*)d_in[6];
    const float* WOw = (const float*)d_in[7];
    const float* WOb = (const float*)d_in[8];
    float* out = (float*)d_out;

    unsigned short* ws  = (unsigned short*)d_ws;
    unsigned short* xb  = ws;
    unsigned short* wqb = xb  + (size_t)MTOT * DM;
    unsigned short* wkb = wqb + (size_t)DM * DM;
    unsigned short* wvb = wkb + (size_t)DM * DM;
    unsigned short* wob = wvb + (size_t)DM * DM;
    unsigned short* Qb  = wob + (size_t)DM * DM;
    unsigned short* Kb  = Qb  + (size_t)MTOT * DM;
    unsigned short* Vb  = Kb  + (size_t)MTOT * DM;   // natural V; reused as ctx
    unsigned short* Vtb = Vb  + (size_t)MTOT * DM;   // V^T (B,H,DK,T)
    unsigned short* ctxb = Vb;                       // alias: V dead after vtrans

    cvt_all_kernel<<<(MTOT*DM)/1024 + 4*(DM*DM)/1024, 256, 0, stream>>>(
        x, WQw, WKw, WVw, WOw, xb, wqb, wkb, wvb, wob);

    gemm_bf16_kernel<1><<<dim3(MTOT/128, DM/128, 3), 256, 0, stream>>>(
        xb, wqb, WQb, wkb, WKb, wvb, WVb, Qb, Kb, Vb);

    vtrans_kernel<<<dim3(TT/64, BB*NH), 256, 0, stream>>>(Vb, Vtb);

    attn_kernel<<<dim3(BB*NH, 8), 256, 0, stream>>>(Qb, Kb, Vtb, ctxb);

    gemm_bf16_kernel<0><<<dim3(MTOT/128, DM/128, 1), 256, 0, stream>>>(
        ctxb, wob, WOb, wob, WOb, wob, WOb, out, out, out);
}

// Round 8
// 254.169 us; speedup vs baseline: 1.3626x; 1.3626x over previous
//
#include <hip/hip_runtime.h>
#include <math.h>

#define DM 1024
#define NH 16
#define DK 64
#define BB 4
#define TT 2048
#define MTOT (BB*TT)   // 8192

typedef __bf16 bf16x8 __attribute__((ext_vector_type(8)));
typedef short  s16x4  __attribute__((ext_vector_type(4)));
typedef float  f32x4  __attribute__((ext_vector_type(4)));

__device__ __forceinline__ short f2bf_s(float f) {
    __bf16 h = (__bf16)f;
    return __builtin_bit_cast(short, h);
}

// async global->LDS, 16B per lane; LDS dst wave-uniform base, lane i -> base+16i
__device__ __forceinline__ void async_copy16(unsigned short* lds, const unsigned short* g) {
    __builtin_amdgcn_global_load_lds(
        (const __attribute__((address_space(1))) unsigned int*)g,
        (__attribute__((address_space(3))) unsigned int*)lds, 16, 0, 0);
}

// ---------------------------------------------------------------------------
// merged fp32 -> bf16 converts
// ---------------------------------------------------------------------------
__global__ __launch_bounds__(256)
void cvt_all_kernel(const float* __restrict__ x,
                    const float* __restrict__ wq, const float* __restrict__ wk,
                    const float* __restrict__ wv, const float* __restrict__ wo,
                    unsigned short* __restrict__ xb,
                    unsigned short* __restrict__ wqb, unsigned short* __restrict__ wkb,
                    unsigned short* __restrict__ wvb, unsigned short* __restrict__ wob)
{
    const int XB = (MTOT * DM) / 1024;   // 8192
    int bz = blockIdx.x;
    const float* src; unsigned short* dst; int blk;
    if (bz < XB) { src = x; dst = xb; blk = bz; }
    else {
        int t = bz - XB, which = t >> 10;
        blk = t & 1023;
        if (which == 0)      { src = wq; dst = wqb; }
        else if (which == 1) { src = wk; dst = wkb; }
        else if (which == 2) { src = wv; dst = wvb; }
        else                 { src = wo; dst = wob; }
    }
    int i = blk * 256 + threadIdx.x;
    float4 v = ((const float4*)src)[i];
    ushort4 o;
    o.x = (unsigned short)f2bf_s(v.x); o.y = (unsigned short)f2bf_s(v.y);
    o.z = (unsigned short)f2bf_s(v.z); o.w = (unsigned short)f2bf_s(v.w);
    ((ushort4*)dst)[i] = o;
}

// ---------------------------------------------------------------------------
// bf16 MFMA GEMM, BK=64, XOR-swizzled LDS, global_load_lds staging.
// MODE 0: fp32 row-major out. MODE 1: bf16 (B,H,T,DK); z=0 Q(+RoPE+prescale),
// z=1 K(+RoPE), z=2 V plain.
// ---------------------------------------------------------------------------
template<int MODE>
__global__ __launch_bounds__(256, 3)
void gemm_bf16_kernel(const unsigned short* __restrict__ X,
                      const unsigned short* __restrict__ W0, const float* __restrict__ b0,
                      const unsigned short* __restrict__ W1, const float* __restrict__ b1,
                      const unsigned short* __restrict__ W2, const float* __restrict__ b2,
                      void* __restrict__ Y0, void* __restrict__ Y1, void* __restrict__ Y2)
{
    const unsigned short* W; const float* bias; void* Yv;
    const int z = blockIdx.z;
    if (z == 0)      { W = W0; bias = b0; Yv = Y0; }
    else if (z == 1) { W = W1; bias = b1; Yv = Y1; }
    else             { W = W2; bias = b2; Yv = Y2; }

    __shared__ __align__(16) unsigned short As[128 * 64];  // 16 KB
    __shared__ __align__(16) unsigned short Bs[128 * 64];  // 16 KB

    const int tid  = threadIdx.x;
    const int w    = tid >> 6, lane = tid & 63;
    const int quad = lane >> 4, lq = lane & 15;
    const int bm = blockIdx.x * 128, bn = blockIdx.y * 128;
    const int wm = (w >> 1) * 64,   wn = (w & 1) * 64;

    const int srow = lane >> 3;                 // 0..7 within the 8-row group
    const int sg   = (lane & 7) ^ srow;         // swizzled source granule
    const int soff = sg * 8;                    // shorts

    f32x4 acc[4][4];
    #pragma unroll
    for (int i = 0; i < 4; ++i)
        #pragma unroll
        for (int j = 0; j < 4; ++j)
            acc[i][j] = {0.f, 0.f, 0.f, 0.f};

    for (int k0 = 0; k0 < DM; k0 += 64) {
        #pragma unroll
        for (int c = 0; c < 4; ++c) {
            int r0 = w * 32 + c * 8;
            async_copy16(&As[r0 * 64], &X[(size_t)(bm + r0 + srow) * DM + k0 + soff]);
            async_copy16(&Bs[r0 * 64], &W[(size_t)(bn + r0 + srow) * DM + k0 + soff]);
        }
        __syncthreads();

        #pragma unroll
        for (int ks = 0; ks < 2; ++ks) {
            const int gsw = ((ks << 2) + quad) ^ (lq & 7);  // physical granule
            bf16x8 af[4], bfr[4];
            #pragma unroll
            for (int i = 0; i < 4; ++i)
                af[i] = *(const bf16x8*)&As[(wm + i*16 + lq) * 64 + gsw * 8];
            #pragma unroll
            for (int j = 0; j < 4; ++j)
                bfr[j] = *(const bf16x8*)&Bs[(wn + j*16 + lq) * 64 + gsw * 8];
            #pragma unroll
            for (int i = 0; i < 4; ++i)
                #pragma unroll
                for (int j = 0; j < 4; ++j)
                    acc[i][j] = __builtin_amdgcn_mfma_f32_16x16x32_bf16(af[i], bfr[j], acc[i][j], 0, 0, 0);
        }
        __syncthreads();
    }

    if (MODE == 0) {
        #pragma unroll
        for (int j = 0; j < 4; ++j) {
            int n = bn + wn + j*16 + lq;
            float bv = bias[n];
            #pragma unroll
            for (int i = 0; i < 4; ++i)
                #pragma unroll
                for (int r = 0; r < 4; ++r) {
                    int m = bm + wm + i*16 + quad*4 + r;
                    ((float*)Yv)[(size_t)m * DM + n] = acc[i][j][r] + bv;
                }
        }
    } else if (z == 2) {
        #pragma unroll
        for (int j = 0; j < 4; ++j) {
            int n = bn + wn + j*16 + lq;
            float bv = bias[n];
            int h = n >> 6, dk = n & 63;
            #pragma unroll
            for (int i = 0; i < 4; ++i)
                #pragma unroll
                for (int r = 0; r < 4; ++r) {
                    int m = bm + wm + i*16 + quad*4 + r;
                    int b = m >> 11, t = m & 2047;
                    ((__bf16*)Yv)[(((size_t)(b * NH + h) * TT + t) << 6) + dk] =
                        (__bf16)(acc[i][j][r] + bv);
                }
        }
    } else {
        // Q (z=0) / K (z=1): fused RoPE; Q also pre-scaled by 0.125*log2e
        const float QSC = (z == 0) ? 0.125f * 1.44269504f : 1.0f;
        const int h = (bn + wn) >> 6;
        #pragma unroll
        for (int jp = 0; jp < 2; ++jp) {
            int dk1 = jp * 16 + lq;                           // 0..31
            float freq = exp2f(-(float)dk1 * 0.4152410118f);  // 10000^(-dk1/32)
            float bv1 = bias[bn + wn + dk1];
            float bv2 = bias[bn + wn + dk1 + 32];
            #pragma unroll
            for (int i = 0; i < 4; ++i) {
                #pragma unroll
                for (int r = 0; r < 4; ++r) {
                    int m = bm + wm + i*16 + quad*4 + r;
                    int b = m >> 11, t = m & 2047;
                    float ang = (float)t * freq;
                    float sn = __sinf(ang), cs = __cosf(ang);
                    float v1 = acc[i][jp][r]     + bv1;
                    float v2 = acc[i][jp + 2][r] + bv2;
                    float o1 = (v1 * cs - v2 * sn) * QSC;
                    float o2 = (v1 * sn + v2 * cs) * QSC;
                    size_t base = ((size_t)(b * NH + h) * TT + t) << 6;
                    ((__bf16*)Yv)[base + dk1]      = (__bf16)o1;
                    ((__bf16*)Yv)[base + dk1 + 32] = (__bf16)o2;
                }
            }
        }
    }
}

// ---------------------------------------------------------------------------
// V (B,H,T,DK) -> V^T (B,H,DK,T), coalesced both sides via LDS tile.
// ---------------------------------------------------------------------------
__global__ __launch_bounds__(256)
void vtrans_kernel(const unsigned short* __restrict__ V, unsigned short* __restrict__ Vt)
{
    __shared__ unsigned short tile[64][72];
    const int tid = threadIdx.x;
    const int t0 = blockIdx.x * 64;
    const int bh = blockIdx.y;
    const size_t ib = (size_t)bh * TT * DK;
    const size_t ob = (size_t)bh * DK * TT;
    #pragma unroll
    for (int p = 0; p < 2; ++p) {
        int s = p * 256 + tid;
        int r = s >> 3, c0 = (s & 7) * 8;
        *(uint4*)&tile[r][c0] = *(const uint4*)&V[ib + (size_t)(t0 + r) * DK + c0];
    }
    __syncthreads();
    #pragma unroll
    for (int p = 0; p < 2; ++p) {
        int s = p * 256 + tid;
        int dk = s >> 3, c0 = (s & 7) * 8;
        unsigned short tmp[8];
        #pragma unroll
        for (int e = 0; e < 8; ++e) tmp[e] = tile[c0 + e][dk];
        *(uint4*)&Vt[ob + (size_t)dk * TT + t0 + c0] = *(const uint4*)tmp;
    }
}

// ---------------------------------------------------------------------------
// MFMA flash attention (causal), S^T form. LDS double-buffered K/V^T staging
// via global_load_lds with XOR swizzle (phys granule = logical ^ (row&7));
// 4 q-tiles per block {x,15-x,16+x,31-x}: one kf/vb fragment set in REGISTERS
// serves 4 q-tiles -> LDS reads amortized 4x. One barrier per iter; prefetch
// issued right after it, landing during compute. Static-max exp2 softmax.
// Grid (64, 8); 2 blocks/CU.
// ---------------------------------------------------------------------------
__global__ __launch_bounds__(256, 2)
void attn_kernel(const unsigned short* __restrict__ Q, const unsigned short* __restrict__ K,
                 const unsigned short* __restrict__ Vt_g, unsigned short* __restrict__ ctx)
{
    __shared__ __align__(16) unsigned short KV[2][2][64 * 64];  // 32 KB

    const int tid  = threadIdx.x;
    const int w    = tid >> 6, lane = tid & 63;
    const int quad = lane >> 4, lq = lane & 15;
    const int bh = blockIdx.x;
    const int x  = blockIdx.y;                  // 0..7
    const int qt[4] = { x, 15 - x, 16 + x, 31 - x };
    const size_t kbase = (size_t)bh * TT * DK;
    const size_t vbase = (size_t)bh * DK * TT;

    // staging geometry (per wave: rows w*16..w*16+15 of each 64x64 tile)
    const int srow = lane >> 3;                 // 0..7
    const int sg   = (lane & 7) ^ srow;         // swizzled source granule
    const unsigned short* Ksrc = &K[kbase + (size_t)(w*16 + srow) * DK + sg*8];
    const unsigned short* Vsrc = &Vt_g[vbase + (size_t)(w*16 + srow) * TT + sg*8];

    auto issue = [&](int kb, int buf) {
        unsigned short* Kd = &KV[buf][0][w*16*64];
        unsigned short* Vd = &KV[buf][1][w*16*64];
        const unsigned short* ks0 = Ksrc + (size_t)kb * 64 * DK;
        const unsigned short* vs0 = Vsrc + (size_t)kb * 64;
        async_copy16(Kd,          ks0);
        async_copy16(Kd + 8*64,   ks0 + 8*DK);
        async_copy16(Vd,          vs0);
        async_copy16(Vd + 8*64,   vs0 + (size_t)8*TT);
    };

    int   qrow[4];
    bf16x8 qf[4][2];
    #pragma unroll
    for (int i = 0; i < 4; ++i) {
        qrow[i] = qt[i]*64 + w*16 + lq;
        qf[i][0] = *(const bf16x8*)&Q[kbase + (size_t)qrow[i] * DK + quad*8];
        qf[i][1] = *(const bf16x8*)&Q[kbase + (size_t)qrow[i] * DK + 32 + quad*8];
    }

    f32x4 accO[4][4];
    float l_i[4] = {0.f, 0.f, 0.f, 0.f};
    #pragma unroll
    for (int i = 0; i < 4; ++i)
        #pragma unroll
        for (int dt = 0; dt < 4; ++dt) accO[i][dt] = {0.f,0.f,0.f,0.f};

    const int kbmax = qt[3];
    issue(0, 0);
    for (int kb = 0; kb <= kbmax; ++kb) {
        __syncthreads();                       // drains this wave's async; readers of other buf done
        if (kb < kbmax) issue(kb + 1, (kb + 1) & 1);

        const unsigned short* Kb_ = &KV[kb & 1][0][0];
        const unsigned short* Vb_ = &KV[kb & 1][1][0];

        // K fragments: row nt*16+lq, logical granule ks*4+quad, swizzled
        bf16x8 kf[2][4];
        #pragma unroll
        for (int ks = 0; ks < 2; ++ks)
            #pragma unroll
            for (int nt = 0; nt < 4; ++nt)
                kf[ks][nt] = *(const bf16x8*)&Kb_[(nt*16 + lq) * 64 +
                                (((ks << 2) + quad) ^ (lq & 7)) * 8];
        // V^T fragments: row dt*16+lq, logical granule 2kt+(quad>>1), +
        // (quad&1)*4 shorts within granule
        s16x4 vb[4][4];
        #pragma unroll
        for (int kt = 0; kt < 4; ++kt)
            #pragma unroll
            for (int dt = 0; dt < 4; ++dt)
                vb[kt][dt] = *(const s16x4*)&Vb_[(dt*16 + lq) * 64 +
                                (((kt << 1) + (quad >> 1)) ^ (lq & 7)) * 8 +
                                (quad & 1) * 4];

        #pragma unroll
        for (int i = 0; i < 4; ++i) {
            if (kb <= qt[i]) {
                f32x4 st[4];
                #pragma unroll
                for (int nt = 0; nt < 4; ++nt) st[nt] = {0.f,0.f,0.f,0.f};
                #pragma unroll
                for (int ks = 0; ks < 2; ++ks)
                    #pragma unroll
                    for (int nt = 0; nt < 4; ++nt)
                        st[nt] = __builtin_amdgcn_mfma_f32_16x16x32_bf16(kf[ks][nt], qf[i][ks], st[nt], 0, 0, 0);
                if (kb == qt[i]) {
                    #pragma unroll
                    for (int nt = 0; nt < 4; ++nt)
                        #pragma unroll
                        for (int r = 0; r < 4; ++r) {
                            int kc = kb*64 + nt*16 + quad*4 + r;
                            if (kc > qrow[i]) st[nt][r] = -1e30f;
                        }
                }
                s16x4 p[4];
                #pragma unroll
                for (int nt = 0; nt < 4; ++nt)
                    #pragma unroll
                    for (int r = 0; r < 4; ++r) {
                        float e = exp2f(st[nt][r]);
                        l_i[i] += e;
                        p[nt][r] = f2bf_s(e);
                    }
                #pragma unroll
                for (int kt = 0; kt < 4; ++kt)
                    #pragma unroll
                    for (int dt = 0; dt < 4; ++dt)
                        accO[i][dt] = __builtin_amdgcn_mfma_f32_16x16x16bf16_1k(p[kt], vb[kt][dt], accO[i][dt], 0, 0, 0);
            }
        }
    }

    // ---- epilogue ----
    const int b = bh >> 4, h = bh & 15;
    #pragma unroll
    for (int i = 0; i < 4; ++i) {
        float l = l_i[i];
        l += __shfl_xor(l, 16, 64);
        l += __shfl_xor(l, 32, 64);
        float linv = 1.0f / l;
        f32x4 il4;
        #pragma unroll
        for (int r = 0; r < 4; ++r) il4[r] = __shfl(linv, quad*4 + r, 64);
        #pragma unroll
        for (int r = 0; r < 4; ++r) {
            int t = qt[i]*64 + w*16 + quad*4 + r;
            size_t ob = ((size_t)b * TT + t) * DM + h * DK;
            #pragma unroll
            for (int dt = 0; dt < 4; ++dt)
                ((__bf16*)ctx)[ob + dt*16 + lq] = (__bf16)(accO[i][dt][r] * il4[r]);
        }
    }
}

// ---------------------------------------------------------------------------
extern "C" void kernel_launch(void* const* d_in, const int* in_sizes, int n_in,
                              void* d_out, int out_size, void* d_ws, size_t ws_size,
                              hipStream_t stream)
{
    const float* x   = (const float*)d_in[0];
    const float* WQw = (const float*)d_in[1];
    const float* WQb = (const float*)d_in[2];
    const float* WKw = (const float*)d_in[3];
    const float* WKb = (const float*)d_in[4];
    const float* WVw = (const float*)d_in[5];
    const float* WVb = (const float*)d_in[6];
    const float* WOw = (const float*)d_in[7];
    const float* WOb = (const float*)d_in[8];
    float* out = (float*)d_out;

    unsigned short* ws  = (unsigned short*)d_ws;
    unsigned short* xb  = ws;
    unsigned short* wqb = xb  + (size_t)MTOT * DM;
    unsigned short* wkb = wqb + (size_t)DM * DM;
    unsigned short* wvb = wkb + (size_t)DM * DM;
    unsigned short* wob = wvb + (size_t)DM * DM;
    unsigned short* Qb  = wob + (size_t)DM * DM;
    unsigned short* Kb  = Qb  + (size_t)MTOT * DM;
    unsigned short* Vb  = Kb  + (size_t)MTOT * DM;   // natural V; reused as ctx
    unsigned short* Vtb = Vb  + (size_t)MTOT * DM;   // V^T (B,H,DK,T)
    unsigned short* ctxb = Vb;                       // alias: V dead after vtrans

    cvt_all_kernel<<<(MTOT*DM)/1024 + 4*(DM*DM)/1024, 256, 0, stream>>>(
        x, WQw, WKw, WVw, WOw, xb, wqb, wkb, wvb, wob);

    gemm_bf16_kernel<1><<<dim3(MTOT/128, DM/128, 3), 256, 0, stream>>>(
        xb, wqb, WQb, wkb, WKb, wvb, WVb, Qb, Kb, Vb);

    vtrans_kernel<<<dim3(TT/64, BB*NH), 256, 0, stream>>>(Vb, Vtb);

    attn_kernel<<<dim3(BB*NH, 8), 256, 0, stream>>>(Qb, Kb, Vtb, ctxb);

    gemm_bf16_kernel<0><<<dim3(MTOT/128, DM/128, 1), 256, 0, stream>>>(
        ctxb, wob, WOb, wob, WOb, wob, WOb, out, out, out);
}